// Round 6
// baseline (871.027 us; speedup 1.0000x reference)
//
#include <hip/hip_runtime.h>

// MoE top-2, E=8, T=8192, H=1024, I=2816. bf16 MFMA grouped-GEMM pipeline.
// R6: fix R5 gateup grid coverage bug (11n x 256-stride but 128-col tiles ->
//     half of hbuf unwritten). Grid now 8e*22n*32m, n0 stride 128.
//     Schedule unchanged: dbuf-2, 4 phases/K-tile, counted vmcnt+barrier, setprio.

#define T_TOK 8192
#define H_DIM 1024
#define I_DIM 2816
#define NEXP  8
#define CAP   8192

typedef short bf16x8 __attribute__((ext_vector_type(8)));
typedef float f32x4  __attribute__((ext_vector_type(4)));

static __device__ __forceinline__ unsigned short f2bf(float f) {
  unsigned u = __float_as_uint(f);
  u = u + 0x7fffu + ((u >> 16) & 1u);   // RNE
  return (unsigned short)(u >> 16);
}

#define MFMA16x16x32(acc, a, b) \
  asm("v_mfma_f32_16x16x32_bf16 %0, %1, %2, %0" : "+v"(acc) : "v"(a), "v"(b))

#define GLD16(g, l) \
  __builtin_amdgcn_global_load_lds((const __attribute__((address_space(1))) void*)(g), \
                                   (__attribute__((address_space(3))) void*)(l), 16, 0, 0)

// counted wait + collective barrier as one un-splittable asm blob
#define WAITBAR(n) asm volatile("s_waitcnt vmcnt(" #n ")\ns_barrier" ::: "memory")

// ---------------- router ----------------
__global__ __launch_bounds__(256) void router_kernel(
    const float* __restrict__ x, const float* __restrict__ wr,
    int* __restrict__ cnt, int* __restrict__ tokL, float* __restrict__ wgtL,
    unsigned short* __restrict__ xb) {
  __shared__ float rw[NEXP * H_DIM];    // 32 KB
  int tid = threadIdx.x;
#pragma unroll
  for (int it = 0; it < 8; ++it) {
    int i4 = it * 256 + tid;
    ((float4*)rw)[i4] = ((const float4*)wr)[i4];
  }
  __syncthreads();
  int wid = tid >> 6, lane = tid & 63;
  int t = blockIdx.x * 4 + wid;
  float a[NEXP];
#pragma unroll
  for (int e = 0; e < NEXP; ++e) a[e] = 0.f;
#pragma unroll
  for (int hc = 0; hc < 4; ++hc) {
    int h = hc * 256 + lane * 4;
    float4 xv = *(const float4*)(x + (size_t)t * H_DIM + h);
    ushort4 o;
    o.x = f2bf(xv.x); o.y = f2bf(xv.y); o.z = f2bf(xv.z); o.w = f2bf(xv.w);
    *(ushort4*)(xb + (size_t)t * H_DIM + h) = o;
#pragma unroll
    for (int e = 0; e < NEXP; ++e) {
      float4 w4 = *(const float4*)(&rw[e * H_DIM + h]);
      a[e] += xv.x * w4.x + xv.y * w4.y + xv.z * w4.z + xv.w * w4.w;
    }
  }
#pragma unroll
  for (int e = 0; e < NEXP; ++e) {
    float v = a[e];
    for (int off = 32; off > 0; off >>= 1) v += __shfl_xor(v, off, 64);
    a[e] = v;
  }
  if (lane == 0) {
    int e1 = 0; float l1 = a[0];
#pragma unroll
    for (int e = 1; e < NEXP; ++e) if (a[e] > l1) { l1 = a[e]; e1 = e; }
    int e2 = -1; float l2 = -3.4e38f;
#pragma unroll
    for (int e = 0; e < NEXP; ++e) if (e != e1 && a[e] > l2) { l2 = a[e]; e2 = e; }
    float q = expf(l2 - l1);
    float w1 = 1.f / (1.f + q);
    float w2 = q * w1;
    int p1 = atomicAdd(&cnt[e1], 1);
    tokL[e1 * CAP + p1] = t; wgtL[e1 * CAP + p1] = w1;
    int p2 = atomicAdd(&cnt[e2], 1);
    tokL[e2 * CAP + p2] = t; wgtL[e2 * CAP + p2] = w2;
  }
}

__global__ void scan_kernel(const int* __restrict__ cnt, int* __restrict__ offs) {
  if (threadIdx.x == 0) {
    int s = 0;
    for (int e = 0; e < NEXP; ++e) { offs[e] = s; s += cnt[e]; }
  }
}

// ---------------- transpose + cast ----------------
__global__ __launch_bounds__(256) void transpose_kernel(
    const float* __restrict__ src, unsigned short* __restrict__ dst, int R, int C) {
  __shared__ float tile[64][65];
  int m = blockIdx.z;
  int r0 = blockIdx.y * 64, c0 = blockIdx.x * 64;
  const float* s = src + (size_t)m * R * C;
  unsigned short* d = dst + (size_t)m * R * C;
  int tid = threadIdx.x;
#pragma unroll
  for (int it = 0; it < 4; ++it) {
    int id4 = it * 256 + tid;
    int r = id4 >> 4, c4 = (id4 & 15) * 4;
    float4 v = *(const float4*)(s + (size_t)(r0 + r) * C + c0 + c4);
    tile[r][c4] = v.x; tile[r][c4 + 1] = v.y; tile[r][c4 + 2] = v.z; tile[r][c4 + 3] = v.w;
  }
  __syncthreads();
#pragma unroll
  for (int it = 0; it < 4; ++it) {
    int qd = it * 256 + tid;
    int c = qd >> 4, rq = (qd & 15) * 4;
    ushort4 o;
    o.x = f2bf(tile[rq][c]);     o.y = f2bf(tile[rq + 1][c]);
    o.z = f2bf(tile[rq + 2][c]); o.w = f2bf(tile[rq + 3][c]);
    *(ushort4*)(d + (size_t)(c0 + c) * R + r0 + rq) = o;
  }
}

// ---------------- gate+up fused grouped GEMM, phase-pipelined ----------------
// BM=256, per-tensor BN=128 (G and U). Issue order/tile: A0 A1 A2 A3 G0 G1 U0 U1.
// Phase 0 entry WAITBAR(2): A+G landed (U outstanding). Phase 2 WAITBAR(4): U landed.
__global__ __launch_bounds__(512, 2) void gateup_kernel(
    const unsigned short* __restrict__ xb,
    const unsigned short* __restrict__ wgT,   // [E][I][H] bf16
    const unsigned short* __restrict__ wuT,
    const int* __restrict__ cnt, const int* __restrict__ offs,
    const int* __restrict__ tokL,
    unsigned short* __restrict__ hbuf) {
  // grid 5632 = 8e * (22n * 32m); XCD chunk = one expert (704 blocks), m fastest
  int flat = blockIdx.x;
  int wg = (flat & 7) * 704 + (flat >> 3);
  int e = wg / 704;
  int r = wg % 704;
  int n0 = (r >> 5) * 128;                    // 22 n-blocks * 128 = 2816 = I_DIM
  int m0 = (r & 31) * 256;
  int cnt_e = cnt[e];
  if (m0 >= cnt_e) return;
  int rcnt = cnt_e - m0; if (rcnt > 256) rcnt = 256;

  __shared__ unsigned short As[2][256 * 64];  // 64 KB
  __shared__ unsigned short Gs[2][128 * 64];  // 32 KB
  __shared__ unsigned short Us[2][128 * 64];  // 32 KB
  __shared__ int trow[256];
  int tid = threadIdx.x;
  if (tid < 256) trow[tid] = tokL[e * CAP + m0 + ((tid < rcnt) ? tid : 0)];
  __syncthreads();

  int lane = tid & 63, wid = tid >> 6;
  int lr = lane >> 3;
  int csrc = ((lane & 7) ^ lr) * 8;           // pre-swizzled source col (shorts)

  const unsigned short* pA[4]; int oA[4];
  const unsigned short* pG[2]; const unsigned short* pU[2]; int oGU[2];
#pragma unroll
  for (int i = 0; i < 4; ++i) {
    int row = i * 64 + wid * 8 + lr;
    pA[i] = xb + (size_t)trow[row] * H_DIM + csrc;
    oA[i] = (i * 64 + wid * 8) * 64;
  }
#pragma unroll
  for (int j = 0; j < 2; ++j) {
    int row = j * 64 + wid * 8 + lr;
    size_t wrow = ((size_t)e * I_DIM + n0 + row) * H_DIM + csrc;
    pG[j] = wgT + wrow; pU[j] = wuT + wrow;
    oGU[j] = (j * 64 + wid * 8) * 64;
  }

  int wr = wid >> 1, wc = wid & 1;            // 4M x 2N waves
  int fr = lane & 15, fg = lane >> 4;
  int fsw = fr & 7;
  int cb[2];
  cb[0] = ((fg) ^ fsw) * 8;
  cb[1] = ((4 + fg) ^ fsw) * 8;

  f32x4 accg[4][4], accu[4][4];
#pragma unroll
  for (int m = 0; m < 4; ++m)
#pragma unroll
    for (int n = 0; n < 4; ++n) { accg[m][n] = (f32x4)0.f; accu[m][n] = (f32x4)0.f; }

  // prologue: stage tile 0 in canonical order
#pragma unroll
  for (int i = 0; i < 4; ++i) GLD16(pA[i], &As[0][oA[i]]);
#pragma unroll
  for (int j = 0; j < 2; ++j) GLD16(pG[j], &Gs[0][oGU[j]]);
#pragma unroll
  for (int j = 0; j < 2; ++j) GLD16(pU[j], &Us[0][oGU[j]]);

  bf16x8 am[4][2], bg[4][2], bu[4][2];
  const int NT = H_DIM / 64;                  // 16

#define GU_READ_AM(lo) _Pragma("unroll") for (int mf = lo; mf < lo + 2; ++mf) \
    _Pragma("unroll") for (int kk = 0; kk < 2; ++kk) \
      am[mf][kk] = *(const bf16x8*)(Ac + (wr * 64 + mf * 16 + fr) * 64 + cb[kk]);
#define GU_READ_B(arr, base) _Pragma("unroll") for (int nf = 0; nf < 4; ++nf) \
    _Pragma("unroll") for (int kk = 0; kk < 2; ++kk) \
      arr[nf][kk] = *(const bf16x8*)(base + (wc * 64 + nf * 16 + fr) * 64 + cb[kk]);
#define GU_MFMA(acc, bb, lo) __builtin_amdgcn_s_setprio(1); \
    _Pragma("unroll") for (int mf = lo; mf < lo + 2; ++mf) \
    _Pragma("unroll") for (int nf = 0; nf < 4; ++nf) \
    _Pragma("unroll") for (int kk = 0; kk < 2; ++kk) \
      MFMA16x16x32(acc[mf][nf], am[mf][kk], bb[nf][kk]); \
    __builtin_amdgcn_s_setprio(0);

  for (int kt = 0; kt < NT - 1; ++kt) {
    int cur = kt & 1, nxt = cur ^ 1;
    int k1 = (kt + 1) * 64;
    const unsigned short* Ac = &As[cur][0];
    const unsigned short* Gc = &Gs[cur][0];
    const unsigned short* Uc = &Us[cur][0];
    WAITBAR(2);                               // A+G of kt landed (U outstanding)
    // phase 0
    GLD16(pA[0] + k1, &As[nxt][oA[0]]);
    GLD16(pA[1] + k1, &As[nxt][oA[1]]);
    GU_READ_AM(0);
    GU_READ_B(bg, Gc);
    GU_MFMA(accg, bg, 0);
    // phase 1
    GLD16(pA[2] + k1, &As[nxt][oA[2]]);
    GLD16(pA[3] + k1, &As[nxt][oA[3]]);
    GU_READ_AM(2);
    GU_MFMA(accg, bg, 2);
    // phase 2
    WAITBAR(4);                               // U of kt landed (A0'..A3' outstanding)
    GLD16(pG[0] + k1, &Gs[nxt][oGU[0]]);
    GLD16(pG[1] + k1, &Gs[nxt][oGU[1]]);
    GU_READ_B(bu, Uc);
    GU_MFMA(accu, bu, 0);
    // phase 3
    GLD16(pU[0] + k1, &Us[nxt][oGU[0]]);
    GLD16(pU[1] + k1, &Us[nxt][oGU[1]]);
    GU_MFMA(accu, bu, 2);
  }
  {                                            // peeled last tile (no staging)
    int cur = (NT - 1) & 1;
    const unsigned short* Ac = &As[cur][0];
    const unsigned short* Gc = &Gs[cur][0];
    const unsigned short* Uc = &Us[cur][0];
    WAITBAR(2);
    GU_READ_AM(0);
    GU_READ_B(bg, Gc);
    GU_MFMA(accg, bg, 0);
    GU_READ_AM(2);
    GU_MFMA(accg, bg, 2);
    WAITBAR(0);
    GU_READ_B(bu, Uc);
    GU_MFMA(accu, bu, 0);
    GU_MFMA(accu, bu, 2);
  }
#undef GU_READ_AM
#undef GU_READ_B
#undef GU_MFMA

  int hb = offs[e];
#pragma unroll
  for (int mf = 0; mf < 4; ++mf)
#pragma unroll
    for (int q = 0; q < 4; ++q) {
      int row = wr * 64 + mf * 16 + fg * 4 + q;
      if (row < rcnt) {
        size_t rbase = (size_t)(hb + m0 + row) * I_DIM + n0 + wc * 64;
#pragma unroll
        for (int nf = 0; nf < 4; ++nf) {
          float g = accg[mf][nf][q], u = accu[mf][nf][q];
          hbuf[rbase + nf * 16 + fr] = f2bf(g / (1.f + expf(-g)) * u);
        }
      }
    }
}

// ---------------- down grouped GEMM, phase-pipelined + weighted scatter-add ----------------
// Issue order per tile: A0 A2 B0 B1 B2 B3 A1 A3.
__global__ __launch_bounds__(512, 2) void down_kernel(
    const unsigned short* __restrict__ hbuf,
    const unsigned short* __restrict__ wdT,   // [E][H][I] bf16
    const int* __restrict__ cnt, const int* __restrict__ offs,
    const int* __restrict__ tokL, const float* __restrict__ wgtL,
    float* __restrict__ out) {
  // grid 1024 = 8e * (4n * 32m); XCD chunk = one expert (128 blocks), m fastest
  int flat = blockIdx.x;
  int wg = (flat & 7) * 128 + (flat >> 3);
  int e = wg / 128;
  int r = wg % 128;
  int n0 = (r >> 5) * 256;
  int m0 = (r & 31) * 256;
  int cnt_e = cnt[e];
  if (m0 >= cnt_e) return;
  int rcnt = cnt_e - m0; if (rcnt > 256) rcnt = 256;
  int hb = offs[e];

  __shared__ unsigned short As[2][256 * 64];  // 64 KB
  __shared__ unsigned short Bs[2][256 * 64];  // 64 KB
  int tid = threadIdx.x, lane = tid & 63, wid = tid >> 6;
  int lr = lane >> 3;
  int csrc = ((lane & 7) ^ lr) * 8;

  const unsigned short* pA[4]; const unsigned short* pB[4];
  int oAB[4];
#pragma unroll
  for (int i = 0; i < 4; ++i) {
    int row = i * 64 + wid * 8 + lr;
    int rowc = (row < rcnt) ? row : (rcnt - 1);
    pA[i] = hbuf + (size_t)(hb + m0 + rowc) * I_DIM + csrc;
    pB[i] = wdT + ((size_t)e * H_DIM + n0 + row) * I_DIM + csrc;
    oAB[i] = (i * 64 + wid * 8) * 64;
  }

  int wr = wid >> 2, wc = wid & 3;            // 2M x 4N waves
  int fr = lane & 15, fg = lane >> 4;
  int fsw = fr & 7;
  int cb[2];
  cb[0] = ((fg) ^ fsw) * 8;
  cb[1] = ((4 + fg) ^ fsw) * 8;

  f32x4 acc[8][4];
#pragma unroll
  for (int m = 0; m < 8; ++m)
#pragma unroll
    for (int n = 0; n < 4; ++n) acc[m][n] = (f32x4)0.f;

  // prologue: canonical order A0 A2 B0 B1 B2 B3 A1 A3
  GLD16(pA[0], &As[0][oAB[0]]);
  GLD16(pA[2], &As[0][oAB[2]]);
#pragma unroll
  for (int j = 0; j < 4; ++j) GLD16(pB[j], &Bs[0][oAB[j]]);
  GLD16(pA[1], &As[0][oAB[1]]);
  GLD16(pA[3], &As[0][oAB[3]]);

  bf16x8 am[8][2], bn[4][2];
  const int NT = I_DIM / 64;                  // 44

#define DN_READ_AM(lo) _Pragma("unroll") for (int mf = lo; mf < lo + 4; ++mf) \
    _Pragma("unroll") for (int kk = 0; kk < 2; ++kk) \
      am[mf][kk] = *(const bf16x8*)(Ac + (wr * 128 + mf * 16 + fr) * 64 + cb[kk]);
#define DN_READ_BN(lo) _Pragma("unroll") for (int nf = lo; nf < lo + 2; ++nf) \
    _Pragma("unroll") for (int kk = 0; kk < 2; ++kk) \
      bn[nf][kk] = *(const bf16x8*)(Bc + (wc * 64 + nf * 16 + fr) * 64 + cb[kk]);
#define DN_MFMA(mlo, nlo) __builtin_amdgcn_s_setprio(1); \
    _Pragma("unroll") for (int mf = mlo; mf < mlo + 4; ++mf) \
    _Pragma("unroll") for (int nf = nlo; nf < nlo + 2; ++nf) \
    _Pragma("unroll") for (int kk = 0; kk < 2; ++kk) \
      MFMA16x16x32(acc[mf][nf], am[mf][kk], bn[nf][kk]); \
    __builtin_amdgcn_s_setprio(0);

  for (int kt = 0; kt < NT - 1; ++kt) {
    int cur = kt & 1, nxt = cur ^ 1;
    int k1 = (kt + 1) * 64;
    const unsigned short* Ac = &As[cur][0];
    const unsigned short* Bc = &Bs[cur][0];
    WAITBAR(2);                               // A0,A2,B0..B3 of kt landed
    // phase 0
    GLD16(pA[0] + k1, &As[nxt][oAB[0]]);
    GLD16(pA[2] + k1, &As[nxt][oAB[2]]);
    DN_READ_AM(0);
    DN_READ_BN(0);
    DN_MFMA(0, 0);
    // phase 1
    GLD16(pB[0] + k1, &Bs[nxt][oAB[0]]);
    GLD16(pB[1] + k1, &Bs[nxt][oAB[1]]);
    DN_READ_BN(2);
    DN_MFMA(0, 2);
    // phase 2
    WAITBAR(4);                               // A1,A3 of kt landed
    GLD16(pB[2] + k1, &Bs[nxt][oAB[2]]);
    GLD16(pB[3] + k1, &Bs[nxt][oAB[3]]);
    DN_READ_AM(4);
    DN_MFMA(4, 0);
    // phase 3
    GLD16(pA[1] + k1, &As[nxt][oAB[1]]);
    GLD16(pA[3] + k1, &As[nxt][oAB[3]]);
    DN_MFMA(4, 2);
  }
  {                                            // peeled last tile
    int cur = (NT - 1) & 1;
    const unsigned short* Ac = &As[cur][0];
    const unsigned short* Bc = &Bs[cur][0];
    WAITBAR(2);
    DN_READ_AM(0);
    DN_READ_BN(0);
    DN_MFMA(0, 0);
    DN_READ_BN(2);
    DN_MFMA(0, 2);
    WAITBAR(0);
    DN_READ_AM(4);
    DN_MFMA(4, 0);
    DN_MFMA(4, 2);
  }
#undef DN_READ_AM
#undef DN_READ_BN
#undef DN_MFMA

#pragma unroll
  for (int mf = 0; mf < 8; ++mf)
#pragma unroll
    for (int q = 0; q < 4; ++q) {
      int row = wr * 128 + mf * 16 + fg * 4 + q;
      if (row < rcnt) {
        float w = wgtL[e * CAP + m0 + row];
        int t = tokL[e * CAP + m0 + row];
        float* obase = out + (size_t)t * H_DIM + n0 + wc * 64;
#pragma unroll
        for (int nf = 0; nf < 4; ++nf)
          atomicAdd(obase + nf * 16 + fr, w * acc[mf][nf][q]);
      }
    }
}

extern "C" void kernel_launch(void* const* d_in, const int* in_sizes, int n_in,
                              void* d_out, int out_size, void* d_ws, size_t ws_size,
                              hipStream_t stream) {
  const float* x   = (const float*)d_in[0];
  const float* wr  = (const float*)d_in[1];
  const float* wg  = (const float*)d_in[2];
  const float* wu  = (const float*)d_in[3];
  const float* wd  = (const float*)d_in[4];
  float* out = (float*)d_out;

  char* ws = (char*)d_ws;
  int*   cnt  = (int*)ws;
  int*   offs = (int*)(ws + 64);
  int*   tokL = (int*)(ws + 1024);
  float* wgtL = (float*)(ws + 1024 + (size_t)NEXP * CAP * 4);
  unsigned short* xb  = (unsigned short*)(ws + (1u << 20));
  unsigned short* wgT = (unsigned short*)(ws + (1u << 20) + (size_t)T_TOK * H_DIM * 2);
  unsigned short* wuT = wgT + (size_t)NEXP * I_DIM * H_DIM;
  unsigned short* wdT = wuT + (size_t)NEXP * I_DIM * H_DIM;
  unsigned short* hbuf = wdT + (size_t)NEXP * H_DIM * I_DIM;

  hipMemsetAsync(ws, 0, 64, stream);
  hipMemsetAsync(d_out, 0, (size_t)out_size * 4, stream);

  router_kernel<<<T_TOK / 4, 256, 0, stream>>>(x, wr, cnt, tokL, wgtL, xb);
  scan_kernel<<<1, 64, 0, stream>>>(cnt, offs);

  transpose_kernel<<<dim3(I_DIM / 64, H_DIM / 64, NEXP), 256, 0, stream>>>(wg, wgT, H_DIM, I_DIM);
  transpose_kernel<<<dim3(I_DIM / 64, H_DIM / 64, NEXP), 256, 0, stream>>>(wu, wuT, H_DIM, I_DIM);
  transpose_kernel<<<dim3(H_DIM / 64, I_DIM / 64, NEXP), 256, 0, stream>>>(wd, wdT, I_DIM, H_DIM);

  gateup_kernel<<<5632, 512, 0, stream>>>(xb, wgT, wuT, cnt, offs, tokL, hbuf);
  down_kernel<<<1024, 512, 0, stream>>>(hbuf, wdT, cnt, offs, tokL, wgtL, out);
}

// Round 7
// 705.945 us; speedup vs baseline: 1.2338x; 1.2338x over previous
//
#include <hip/hip_runtime.h>

// MoE top-2, E=8, T=8192, H=1024, I=2816. bf16 MFMA grouped-GEMM pipeline.
// R7: consolidation. R2-exact GEMM structure (stage->sync->compute->sync, 128^2 tiles,
//     48KB LDS, 3 blocks/CU) + XCD expert-chunk swizzle (one expert per XCD, m-fastest)
//     + fused gate/up transpose + vectorized router.

#define T_TOK 8192
#define H_DIM 1024
#define I_DIM 2816
#define NEXP  8
#define CAP   8192

typedef short bf16x8 __attribute__((ext_vector_type(8)));
typedef float f32x4  __attribute__((ext_vector_type(4)));

static __device__ __forceinline__ unsigned short f2bf(float f) {
  unsigned u = __float_as_uint(f);
  u = u + 0x7fffu + ((u >> 16) & 1u);   // RNE
  return (unsigned short)(u >> 16);
}

#define MFMA16x16x32(acc, a, b) \
  asm("v_mfma_f32_16x16x32_bf16 %0, %1, %2, %0" : "+v"(acc) : "v"(a), "v"(b))

#define GLD16(g, l) \
  __builtin_amdgcn_global_load_lds((const __attribute__((address_space(1))) void*)(g), \
                                   (__attribute__((address_space(3))) void*)(l), 16, 0, 0)

// ---------------- router: logits, top-2 softmax, expert lists, x->bf16 ----------------
__global__ __launch_bounds__(256) void router_kernel(
    const float* __restrict__ x, const float* __restrict__ wr,
    int* __restrict__ cnt, int* __restrict__ tokL, float* __restrict__ wgtL,
    unsigned short* __restrict__ xb) {
  __shared__ float rw[NEXP * H_DIM];    // 32 KB
  int tid = threadIdx.x;
#pragma unroll
  for (int it = 0; it < 8; ++it) {
    int i4 = it * 256 + tid;
    ((float4*)rw)[i4] = ((const float4*)wr)[i4];
  }
  __syncthreads();
  int wid = tid >> 6, lane = tid & 63;
  int t = blockIdx.x * 4 + wid;         // one wave per token
  float a[NEXP];
#pragma unroll
  for (int e = 0; e < NEXP; ++e) a[e] = 0.f;
#pragma unroll
  for (int hc = 0; hc < 4; ++hc) {
    int h = hc * 256 + lane * 4;
    float4 xv = *(const float4*)(x + (size_t)t * H_DIM + h);
    ushort4 o;
    o.x = f2bf(xv.x); o.y = f2bf(xv.y); o.z = f2bf(xv.z); o.w = f2bf(xv.w);
    *(ushort4*)(xb + (size_t)t * H_DIM + h) = o;
#pragma unroll
    for (int e = 0; e < NEXP; ++e) {
      float4 w4 = *(const float4*)(&rw[e * H_DIM + h]);
      a[e] += xv.x * w4.x + xv.y * w4.y + xv.z * w4.z + xv.w * w4.w;
    }
  }
#pragma unroll
  for (int e = 0; e < NEXP; ++e) {
    float v = a[e];
    for (int off = 32; off > 0; off >>= 1) v += __shfl_xor(v, off, 64);
    a[e] = v;
  }
  if (lane == 0) {
    int e1 = 0; float l1 = a[0];
#pragma unroll
    for (int e = 1; e < NEXP; ++e) if (a[e] > l1) { l1 = a[e]; e1 = e; }
    int e2 = -1; float l2 = -3.4e38f;
#pragma unroll
    for (int e = 0; e < NEXP; ++e) if (e != e1 && a[e] > l2) { l2 = a[e]; e2 = e; }
    float q = expf(l2 - l1);
    float w1 = 1.f / (1.f + q);
    float w2 = q * w1;
    int p1 = atomicAdd(&cnt[e1], 1);
    tokL[e1 * CAP + p1] = t; wgtL[e1 * CAP + p1] = w1;
    int p2 = atomicAdd(&cnt[e2], 1);
    tokL[e2 * CAP + p2] = t; wgtL[e2 * CAP + p2] = w2;
  }
}

__global__ void scan_kernel(const int* __restrict__ cnt, int* __restrict__ offs) {
  if (threadIdx.x == 0) {
    int s = 0;
    for (int e = 0; e < NEXP; ++e) { offs[e] = s; s += cnt[e]; }
  }
}

// ---------------- fused gate+up transpose: [8][1024][2816] f32 -> [8][2816][1024] bf16 x2 ----------------
__global__ __launch_bounds__(256) void transposeGU_kernel(
    const float* __restrict__ s1, const float* __restrict__ s2,
    unsigned short* __restrict__ d1, unsigned short* __restrict__ d2) {
  __shared__ float tile[64][65];
  int z = blockIdx.z;
  int m = z & 7;
  const float* src = (z < 8) ? s1 : s2;
  unsigned short* dst = (z < 8) ? d1 : d2;
  const int R = H_DIM, C = I_DIM;
  int r0 = blockIdx.y * 64, c0 = blockIdx.x * 64;
  const float* s = src + (size_t)m * R * C;
  unsigned short* d = dst + (size_t)m * R * C;
  int tid = threadIdx.x;
#pragma unroll
  for (int it = 0; it < 4; ++it) {
    int id4 = it * 256 + tid;
    int r = id4 >> 4, c4 = (id4 & 15) * 4;
    float4 v = *(const float4*)(s + (size_t)(r0 + r) * C + c0 + c4);
    tile[r][c4] = v.x; tile[r][c4 + 1] = v.y; tile[r][c4 + 2] = v.z; tile[r][c4 + 3] = v.w;
  }
  __syncthreads();
#pragma unroll
  for (int it = 0; it < 4; ++it) {
    int qd = it * 256 + tid;
    int c = qd >> 4, rq = (qd & 15) * 4;
    ushort4 o;
    o.x = f2bf(tile[rq][c]);     o.y = f2bf(tile[rq + 1][c]);
    o.z = f2bf(tile[rq + 2][c]); o.w = f2bf(tile[rq + 3][c]);
    *(ushort4*)(d + (size_t)(c0 + c) * R + r0 + rq) = o;
  }
}

// ---------------- generic transpose (for w_down) ----------------
__global__ __launch_bounds__(256) void transpose_kernel(
    const float* __restrict__ src, unsigned short* __restrict__ dst, int R, int C) {
  __shared__ float tile[64][65];
  int m = blockIdx.z;
  int r0 = blockIdx.y * 64, c0 = blockIdx.x * 64;
  const float* s = src + (size_t)m * R * C;
  unsigned short* d = dst + (size_t)m * R * C;
  int tid = threadIdx.x;
#pragma unroll
  for (int it = 0; it < 4; ++it) {
    int id4 = it * 256 + tid;
    int r = id4 >> 4, c4 = (id4 & 15) * 4;
    float4 v = *(const float4*)(s + (size_t)(r0 + r) * C + c0 + c4);
    tile[r][c4] = v.x; tile[r][c4 + 1] = v.y; tile[r][c4 + 2] = v.z; tile[r][c4 + 3] = v.w;
  }
  __syncthreads();
#pragma unroll
  for (int it = 0; it < 4; ++it) {
    int qd = it * 256 + tid;
    int c = qd >> 4, rq = (qd & 15) * 4;
    ushort4 o;
    o.x = f2bf(tile[rq][c]);     o.y = f2bf(tile[rq + 1][c]);
    o.z = f2bf(tile[rq + 2][c]); o.w = f2bf(tile[rq + 3][c]);
    *(ushort4*)(d + (size_t)(c0 + c) * R + r0 + rq) = o;
  }
}

// ---------------- gate+up fused grouped GEMM + silu*mul -> h (bf16) ----------------
// R2 structure exact. LDS linear [128][64] bf16; physical (row,c16) holds logical
// (row, c16^(row&7)); staged via GLD16 with pre-swizzled global source col.
__global__ __launch_bounds__(256) void gateup_kernel(
    const unsigned short* __restrict__ xb,
    const unsigned short* __restrict__ wgT,   // [E][I][H] bf16
    const unsigned short* __restrict__ wuT,
    const int* __restrict__ cnt, const int* __restrict__ offs,
    const int* __restrict__ tokL,
    unsigned short* __restrict__ hbuf) {
  // grid 11264 = 8e * 22n * 64m; XCD chunk = one expert (1408 blocks), m fastest
  int flat = blockIdx.x;
  int wg = (flat & 7) * 1408 + (flat >> 3);
  int e = wg / 1408;
  int r = wg % 1408;
  int n0 = (r >> 6) * 128;
  int m0 = (r & 63) * 128;
  int cnt_e = cnt[e];
  if (m0 >= cnt_e) return;
  int rcnt = cnt_e - m0; if (rcnt > 128) rcnt = 128;

  __shared__ unsigned short As[128 * 64], Gs[128 * 64], Us[128 * 64];  // 48 KB
  __shared__ int trow[128];
  int tid = threadIdx.x;
  if (tid < 128) trow[tid] = tokL[e * CAP + m0 + ((tid < rcnt) ? tid : 0)];
  __syncthreads();

  int lane = tid & 63, wid = tid >> 6;
  int lr = lane >> 3;
  int csrc = ((lane & 7) ^ lr) * 8;          // pre-swizzled source col (shorts)

  const unsigned short* baseA[4];
  const unsigned short* baseG[4];
  const unsigned short* baseU[4];
  int ldso[4];
#pragma unroll
  for (int i = 0; i < 4; ++i) {
    int chunk = i * 4 + wid;
    int row = chunk * 8 + lr;
    baseA[i] = xb + (size_t)trow[row] * H_DIM + csrc;
    size_t wrow = ((size_t)e * I_DIM + n0 + row) * H_DIM + csrc;
    baseG[i] = wgT + wrow;
    baseU[i] = wuT + wrow;
    ldso[i] = chunk * 512;
  }

  int wr = wid >> 1, wc = wid & 1;
  int fr = lane & 15, fg = lane >> 4;
  int fsw = fr & 7;

  f32x4 accg[4][4], accu[4][4];
#pragma unroll
  for (int m = 0; m < 4; ++m)
#pragma unroll
    for (int n = 0; n < 4; ++n) { accg[m][n] = (f32x4)0.f; accu[m][n] = (f32x4)0.f; }

  for (int ks = 0; ks < H_DIM / 64; ++ks) {
    int k0 = ks * 64;
#pragma unroll
    for (int i = 0; i < 4; ++i) {
      GLD16(baseA[i] + k0, As + ldso[i]);
      GLD16(baseG[i] + k0, Gs + ldso[i]);
      GLD16(baseU[i] + k0, Us + ldso[i]);
    }
    __syncthreads();
#pragma unroll
    for (int kk = 0; kk < 2; ++kk) {
      int cb = ((kk * 4 + fg) ^ fsw) * 8;
      bf16x8 am[4], bg[4], bu[4];
#pragma unroll
      for (int m = 0; m < 4; ++m)
        am[m] = *(const bf16x8*)(As + (wr * 64 + m * 16 + fr) * 64 + cb);
#pragma unroll
      for (int n = 0; n < 4; ++n) {
        bg[n] = *(const bf16x8*)(Gs + (wc * 64 + n * 16 + fr) * 64 + cb);
        bu[n] = *(const bf16x8*)(Us + (wc * 64 + n * 16 + fr) * 64 + cb);
      }
#pragma unroll
      for (int m = 0; m < 4; ++m)
#pragma unroll
        for (int n = 0; n < 4; ++n) {
          MFMA16x16x32(accg[m][n], am[m], bg[n]);
          MFMA16x16x32(accu[m][n], am[m], bu[n]);
        }
    }
    __syncthreads();
  }
  int hb = offs[e];
#pragma unroll
  for (int m = 0; m < 4; ++m)
#pragma unroll
    for (int q = 0; q < 4; ++q) {
      int row = wr * 64 + m * 16 + fg * 4 + q;
      if (row < rcnt) {
        size_t rbase = (size_t)(hb + m0 + row) * I_DIM + n0 + wc * 64;
#pragma unroll
        for (int n = 0; n < 4; ++n) {
          float g = accg[m][n][q], u = accu[m][n][q];
          hbuf[rbase + n * 16 + fr] = f2bf(g / (1.f + expf(-g)) * u);
        }
      }
    }
}

// ---------------- down grouped GEMM + weighted scatter-add ----------------
__global__ __launch_bounds__(256) void down_kernel(
    const unsigned short* __restrict__ hbuf,
    const unsigned short* __restrict__ wdT,   // [E][H][I] bf16
    const int* __restrict__ cnt, const int* __restrict__ offs,
    const int* __restrict__ tokL, const float* __restrict__ wgtL,
    float* __restrict__ out) {
  // grid 4096 = 8e * 8n * 64m; XCD chunk = one expert (512 blocks), m fastest
  int flat = blockIdx.x;
  int wg = (flat & 7) * 512 + (flat >> 3);
  int e = wg / 512;
  int r = wg % 512;
  int n0 = (r >> 6) * 128;
  int m0 = (r & 63) * 128;
  int cnt_e = cnt[e];
  if (m0 >= cnt_e) return;
  int rcnt = cnt_e - m0; if (rcnt > 128) rcnt = 128;
  int hb = offs[e];

  __shared__ unsigned short As[128 * 64], Bs[128 * 64];   // 32 KB
  int tid = threadIdx.x, lane = tid & 63, wid = tid >> 6;
  int lr = lane >> 3;
  int csrc = ((lane & 7) ^ lr) * 8;

  const unsigned short* baseA[4];
  const unsigned short* baseB[4];
  int ldso[4];
#pragma unroll
  for (int i = 0; i < 4; ++i) {
    int chunk = i * 4 + wid;
    int row = chunk * 8 + lr;
    int rowc = (row < rcnt) ? row : (rcnt - 1);           // clamp: stay in-expert
    baseA[i] = hbuf + (size_t)(hb + m0 + rowc) * I_DIM + csrc;
    baseB[i] = wdT + ((size_t)e * H_DIM + n0 + row) * I_DIM + csrc;
    ldso[i] = chunk * 512;
  }

  int wr = wid >> 1, wc = wid & 1, fr = lane & 15, fg = lane >> 4;
  int fsw = fr & 7;

  f32x4 acc[4][4];
#pragma unroll
  for (int m = 0; m < 4; ++m)
#pragma unroll
    for (int n = 0; n < 4; ++n) acc[m][n] = (f32x4)0.f;

  for (int ks = 0; ks < I_DIM / 64; ++ks) {   // 44 steps
    int k0 = ks * 64;
#pragma unroll
    for (int i = 0; i < 4; ++i) {
      GLD16(baseA[i] + k0, As + ldso[i]);
      GLD16(baseB[i] + k0, Bs + ldso[i]);
    }
    __syncthreads();
#pragma unroll
    for (int kk = 0; kk < 2; ++kk) {
      int cb = ((kk * 4 + fg) ^ fsw) * 8;
      bf16x8 am[4], bn[4];
#pragma unroll
      for (int m = 0; m < 4; ++m)
        am[m] = *(const bf16x8*)(As + (wr * 64 + m * 16 + fr) * 64 + cb);
#pragma unroll
      for (int n = 0; n < 4; ++n)
        bn[n] = *(const bf16x8*)(Bs + (wc * 64 + n * 16 + fr) * 64 + cb);
#pragma unroll
      for (int m = 0; m < 4; ++m)
#pragma unroll
        for (int n = 0; n < 4; ++n)
          MFMA16x16x32(acc[m][n], am[m], bn[n]);
    }
    __syncthreads();
  }
#pragma unroll
  for (int m = 0; m < 4; ++m)
#pragma unroll
    for (int q = 0; q < 4; ++q) {
      int row = wr * 64 + m * 16 + fg * 4 + q;
      if (row < rcnt) {
        float w = wgtL[e * CAP + m0 + row];
        int t = tokL[e * CAP + m0 + row];
        float* obase = out + (size_t)t * H_DIM + n0 + wc * 64;
#pragma unroll
        for (int n = 0; n < 4; ++n)
          atomicAdd(obase + n * 16 + fr, w * acc[m][n][q]);
      }
    }
}

extern "C" void kernel_launch(void* const* d_in, const int* in_sizes, int n_in,
                              void* d_out, int out_size, void* d_ws, size_t ws_size,
                              hipStream_t stream) {
  const float* x   = (const float*)d_in[0];
  const float* wr  = (const float*)d_in[1];
  const float* wg  = (const float*)d_in[2];
  const float* wu  = (const float*)d_in[3];
  const float* wd  = (const float*)d_in[4];
  float* out = (float*)d_out;

  char* ws = (char*)d_ws;
  int*   cnt  = (int*)ws;
  int*   offs = (int*)(ws + 64);
  int*   tokL = (int*)(ws + 1024);
  float* wgtL = (float*)(ws + 1024 + (size_t)NEXP * CAP * 4);
  unsigned short* xb  = (unsigned short*)(ws + (1u << 20));
  unsigned short* wgT = (unsigned short*)(ws + (1u << 20) + (size_t)T_TOK * H_DIM * 2);
  unsigned short* wuT = wgT + (size_t)NEXP * I_DIM * H_DIM;
  unsigned short* wdT = wuT + (size_t)NEXP * I_DIM * H_DIM;
  unsigned short* hbuf = wdT + (size_t)NEXP * H_DIM * I_DIM;

  hipMemsetAsync(ws, 0, 64, stream);
  hipMemsetAsync(d_out, 0, (size_t)out_size * 4, stream);

  router_kernel<<<T_TOK / 4, 256, 0, stream>>>(x, wr, cnt, tokL, wgtL, xb);
  scan_kernel<<<1, 64, 0, stream>>>(cnt, offs);

  transposeGU_kernel<<<dim3(I_DIM / 64, H_DIM / 64, 16), 256, 0, stream>>>(wg, wu, wgT, wuT);
  transpose_kernel<<<dim3(H_DIM / 64, I_DIM / 64, NEXP), 256, 0, stream>>>(wd, wdT, I_DIM, H_DIM);

  gateup_kernel<<<11264, 256, 0, stream>>>(xb, wgT, wuT, cnt, offs, tokL, hbuf);
  down_kernel<<<4096, 256, 0, stream>>>(hbuf, wdT, cnt, offs, tokL, wgtL, out);
}

// Round 8
// 673.890 us; speedup vs baseline: 1.2925x; 1.0476x over previous
//
#include <hip/hip_runtime.h>

// MoE top-2, E=8, T=8192, H=1024, I=2816. bf16 MFMA grouped-GEMM pipeline.
// R8: revert XCD swizzle (weights are L3-resident; swizzle was net-negative).
//     Down GEMM: atomics removed -> plain bf16 stores to compact y[slot];
//     new gather-combine kernel out[t] = w1*y[slot1] + w2*y[slot2]. No out memset.

#define T_TOK 8192
#define H_DIM 1024
#define I_DIM 2816
#define NEXP  8
#define CAP   8192

typedef short bf16x8 __attribute__((ext_vector_type(8)));
typedef float f32x4  __attribute__((ext_vector_type(4)));

static __device__ __forceinline__ unsigned short f2bf(float f) {
  unsigned u = __float_as_uint(f);
  u = u + 0x7fffu + ((u >> 16) & 1u);   // RNE
  return (unsigned short)(u >> 16);
}
static __device__ __forceinline__ float bf2f(unsigned short u) {
  unsigned v = ((unsigned)u) << 16;
  return __uint_as_float(v);
}

#define MFMA16x16x32(acc, a, b) \
  asm("v_mfma_f32_16x16x32_bf16 %0, %1, %2, %0" : "+v"(acc) : "v"(a), "v"(b))

#define GLD16(g, l) \
  __builtin_amdgcn_global_load_lds((const __attribute__((address_space(1))) void*)(g), \
                                   (__attribute__((address_space(3))) void*)(l), 16, 0, 0)

// ---------------- router: logits, top-2 softmax, expert lists + token->slot map ----------------
__global__ __launch_bounds__(256) void router_kernel(
    const float* __restrict__ x, const float* __restrict__ wr,
    int* __restrict__ cnt, int* __restrict__ tokL,
    int* __restrict__ sA, int* __restrict__ sB,
    float* __restrict__ wA, float* __restrict__ wB,
    unsigned short* __restrict__ xb) {
  __shared__ float rw[NEXP * H_DIM];    // 32 KB
  int tid = threadIdx.x;
#pragma unroll
  for (int it = 0; it < 8; ++it) {
    int i4 = it * 256 + tid;
    ((float4*)rw)[i4] = ((const float4*)wr)[i4];
  }
  __syncthreads();
  int wid = tid >> 6, lane = tid & 63;
  int t = blockIdx.x * 4 + wid;         // one wave per token
  float a[NEXP];
#pragma unroll
  for (int e = 0; e < NEXP; ++e) a[e] = 0.f;
#pragma unroll
  for (int hc = 0; hc < 4; ++hc) {
    int h = hc * 256 + lane * 4;
    float4 xv = *(const float4*)(x + (size_t)t * H_DIM + h);
    ushort4 o;
    o.x = f2bf(xv.x); o.y = f2bf(xv.y); o.z = f2bf(xv.z); o.w = f2bf(xv.w);
    *(ushort4*)(xb + (size_t)t * H_DIM + h) = o;
#pragma unroll
    for (int e = 0; e < NEXP; ++e) {
      float4 w4 = *(const float4*)(&rw[e * H_DIM + h]);
      a[e] += xv.x * w4.x + xv.y * w4.y + xv.z * w4.z + xv.w * w4.w;
    }
  }
#pragma unroll
  for (int e = 0; e < NEXP; ++e) {
    float v = a[e];
    for (int off = 32; off > 0; off >>= 1) v += __shfl_xor(v, off, 64);
    a[e] = v;
  }
  if (lane == 0) {
    int e1 = 0; float l1 = a[0];
#pragma unroll
    for (int e = 1; e < NEXP; ++e) if (a[e] > l1) { l1 = a[e]; e1 = e; }
    int e2 = -1; float l2 = -3.4e38f;
#pragma unroll
    for (int e = 0; e < NEXP; ++e) if (e != e1 && a[e] > l2) { l2 = a[e]; e2 = e; }
    float q = expf(l2 - l1);
    float w1 = 1.f / (1.f + q);
    float w2 = q * w1;
    int p1 = atomicAdd(&cnt[e1], 1);
    tokL[e1 * CAP + p1] = t;
    int p2 = atomicAdd(&cnt[e2], 1);
    tokL[e2 * CAP + p2] = t;
    sA[t] = e1 * CAP + p1; wA[t] = w1;
    sB[t] = e2 * CAP + p2; wB[t] = w2;
  }
}

__global__ void scan_kernel(const int* __restrict__ cnt, int* __restrict__ offs) {
  if (threadIdx.x == 0) {
    int s = 0;
    for (int e = 0; e < NEXP; ++e) { offs[e] = s; s += cnt[e]; }
  }
}

// ---------------- fused gate+up transpose: [8][1024][2816] f32 -> [8][2816][1024] bf16 x2 ----------------
__global__ __launch_bounds__(256) void transposeGU_kernel(
    const float* __restrict__ s1, const float* __restrict__ s2,
    unsigned short* __restrict__ d1, unsigned short* __restrict__ d2) {
  __shared__ float tile[64][65];
  int z = blockIdx.z;
  int m = z & 7;
  const float* src = (z < 8) ? s1 : s2;
  unsigned short* dst = (z < 8) ? d1 : d2;
  const int R = H_DIM, C = I_DIM;
  int r0 = blockIdx.y * 64, c0 = blockIdx.x * 64;
  const float* s = src + (size_t)m * R * C;
  unsigned short* d = dst + (size_t)m * R * C;
  int tid = threadIdx.x;
#pragma unroll
  for (int it = 0; it < 4; ++it) {
    int id4 = it * 256 + tid;
    int r = id4 >> 4, c4 = (id4 & 15) * 4;
    float4 v = *(const float4*)(s + (size_t)(r0 + r) * C + c0 + c4);
    tile[r][c4] = v.x; tile[r][c4 + 1] = v.y; tile[r][c4 + 2] = v.z; tile[r][c4 + 3] = v.w;
  }
  __syncthreads();
#pragma unroll
  for (int it = 0; it < 4; ++it) {
    int qd = it * 256 + tid;
    int c = qd >> 4, rq = (qd & 15) * 4;
    ushort4 o;
    o.x = f2bf(tile[rq][c]);     o.y = f2bf(tile[rq + 1][c]);
    o.z = f2bf(tile[rq + 2][c]); o.w = f2bf(tile[rq + 3][c]);
    *(ushort4*)(d + (size_t)(c0 + c) * R + r0 + rq) = o;
  }
}

// ---------------- generic transpose (for w_down) ----------------
__global__ __launch_bounds__(256) void transpose_kernel(
    const float* __restrict__ src, unsigned short* __restrict__ dst, int R, int C) {
  __shared__ float tile[64][65];
  int m = blockIdx.z;
  int r0 = blockIdx.y * 64, c0 = blockIdx.x * 64;
  const float* s = src + (size_t)m * R * C;
  unsigned short* d = dst + (size_t)m * R * C;
  int tid = threadIdx.x;
#pragma unroll
  for (int it = 0; it < 4; ++it) {
    int id4 = it * 256 + tid;
    int r = id4 >> 4, c4 = (id4 & 15) * 4;
    float4 v = *(const float4*)(s + (size_t)(r0 + r) * C + c0 + c4);
    tile[r][c4] = v.x; tile[r][c4 + 1] = v.y; tile[r][c4 + 2] = v.z; tile[r][c4 + 3] = v.w;
  }
  __syncthreads();
#pragma unroll
  for (int it = 0; it < 4; ++it) {
    int qd = it * 256 + tid;
    int c = qd >> 4, rq = (qd & 15) * 4;
    ushort4 o;
    o.x = f2bf(tile[rq][c]);     o.y = f2bf(tile[rq + 1][c]);
    o.z = f2bf(tile[rq + 2][c]); o.w = f2bf(tile[rq + 3][c]);
    *(ushort4*)(d + (size_t)(c0 + c) * R + r0 + rq) = o;
  }
}

// ---------------- gate+up fused grouped GEMM + silu*mul -> h (bf16) ----------------
// R2-exact structure. LDS linear [128][64] bf16; physical (row,c16) holds logical
// (row, c16^(row&7)); staged via GLD16 with pre-swizzled global source col.
__global__ __launch_bounds__(256) void gateup_kernel(
    const unsigned short* __restrict__ xb,
    const unsigned short* __restrict__ wgT,   // [E][I][H] bf16
    const unsigned short* __restrict__ wuT,
    const int* __restrict__ cnt, const int* __restrict__ offs,
    const int* __restrict__ tokL,
    unsigned short* __restrict__ hbuf) {
  int e = blockIdx.z;
  int cnt_e = cnt[e];
  int m0 = blockIdx.y * 128;
  if (m0 >= cnt_e) return;
  int n0 = blockIdx.x * 128;
  int rcnt = cnt_e - m0; if (rcnt > 128) rcnt = 128;

  __shared__ unsigned short As[128 * 64], Gs[128 * 64], Us[128 * 64];  // 48 KB
  __shared__ int trow[128];
  int tid = threadIdx.x;
  if (tid < 128) trow[tid] = tokL[e * CAP + m0 + ((tid < rcnt) ? tid : 0)];
  __syncthreads();

  int lane = tid & 63, wid = tid >> 6;
  int lr = lane >> 3;
  int csrc = ((lane & 7) ^ lr) * 8;          // pre-swizzled source col (shorts)

  const unsigned short* baseA[4];
  const unsigned short* baseG[4];
  const unsigned short* baseU[4];
  int ldso[4];
#pragma unroll
  for (int i = 0; i < 4; ++i) {
    int chunk = i * 4 + wid;
    int row = chunk * 8 + lr;
    baseA[i] = xb + (size_t)trow[row] * H_DIM + csrc;
    size_t wrow = ((size_t)e * I_DIM + n0 + row) * H_DIM + csrc;
    baseG[i] = wgT + wrow;
    baseU[i] = wuT + wrow;
    ldso[i] = chunk * 512;
  }

  int wr = wid >> 1, wc = wid & 1;
  int fr = lane & 15, fg = lane >> 4;
  int fsw = fr & 7;

  f32x4 accg[4][4], accu[4][4];
#pragma unroll
  for (int m = 0; m < 4; ++m)
#pragma unroll
    for (int n = 0; n < 4; ++n) { accg[m][n] = (f32x4)0.f; accu[m][n] = (f32x4)0.f; }

  for (int ks = 0; ks < H_DIM / 64; ++ks) {
    int k0 = ks * 64;
#pragma unroll
    for (int i = 0; i < 4; ++i) {
      GLD16(baseA[i] + k0, As + ldso[i]);
      GLD16(baseG[i] + k0, Gs + ldso[i]);
      GLD16(baseU[i] + k0, Us + ldso[i]);
    }
    __syncthreads();
#pragma unroll
    for (int kk = 0; kk < 2; ++kk) {
      int cb = ((kk * 4 + fg) ^ fsw) * 8;
      bf16x8 am[4], bg[4], bu[4];
#pragma unroll
      for (int m = 0; m < 4; ++m)
        am[m] = *(const bf16x8*)(As + (wr * 64 + m * 16 + fr) * 64 + cb);
#pragma unroll
      for (int n = 0; n < 4; ++n) {
        bg[n] = *(const bf16x8*)(Gs + (wc * 64 + n * 16 + fr) * 64 + cb);
        bu[n] = *(const bf16x8*)(Us + (wc * 64 + n * 16 + fr) * 64 + cb);
      }
#pragma unroll
      for (int m = 0; m < 4; ++m)
#pragma unroll
        for (int n = 0; n < 4; ++n) {
          MFMA16x16x32(accg[m][n], am[m], bg[n]);
          MFMA16x16x32(accu[m][n], am[m], bu[n]);
        }
    }
    __syncthreads();
  }
  int hb = offs[e];
#pragma unroll
  for (int m = 0; m < 4; ++m)
#pragma unroll
    for (int q = 0; q < 4; ++q) {
      int row = wr * 64 + m * 16 + fg * 4 + q;
      if (row < rcnt) {
        size_t rbase = (size_t)(hb + m0 + row) * I_DIM + n0 + wc * 64;
#pragma unroll
        for (int n = 0; n < 4; ++n) {
          float g = accg[m][n][q], u = accu[m][n][q];
          hbuf[rbase + n * 16 + fr] = f2bf(g / (1.f + expf(-g)) * u);
        }
      }
    }
}

// ---------------- down grouped GEMM -> y[slot] (bf16, plain stores) ----------------
__global__ __launch_bounds__(256) void down_kernel(
    const unsigned short* __restrict__ hbuf,
    const unsigned short* __restrict__ wdT,   // [E][H][I] bf16
    const int* __restrict__ cnt, const int* __restrict__ offs,
    unsigned short* __restrict__ y) {         // [16384][H] bf16 compact rows
  int e = blockIdx.z;
  int cnt_e = cnt[e];
  int m0 = blockIdx.y * 128;
  if (m0 >= cnt_e) return;
  int n0 = blockIdx.x * 128;
  int rcnt = cnt_e - m0; if (rcnt > 128) rcnt = 128;
  int hb = offs[e];

  __shared__ unsigned short As[128 * 64], Bs[128 * 64];   // 32 KB
  int tid = threadIdx.x, lane = tid & 63, wid = tid >> 6;
  int lr = lane >> 3;
  int csrc = ((lane & 7) ^ lr) * 8;

  const unsigned short* baseA[4];
  const unsigned short* baseB[4];
  int ldso[4];
#pragma unroll
  for (int i = 0; i < 4; ++i) {
    int chunk = i * 4 + wid;
    int row = chunk * 8 + lr;
    int rowc = (row < rcnt) ? row : (rcnt - 1);           // clamp: stay in-expert
    baseA[i] = hbuf + (size_t)(hb + m0 + rowc) * I_DIM + csrc;
    baseB[i] = wdT + ((size_t)e * H_DIM + n0 + row) * I_DIM + csrc;
    ldso[i] = chunk * 512;
  }

  int wr = wid >> 1, wc = wid & 1, fr = lane & 15, fg = lane >> 4;
  int fsw = fr & 7;

  f32x4 acc[4][4];
#pragma unroll
  for (int m = 0; m < 4; ++m)
#pragma unroll
    for (int n = 0; n < 4; ++n) acc[m][n] = (f32x4)0.f;

  for (int ks = 0; ks < I_DIM / 64; ++ks) {   // 44 steps
    int k0 = ks * 64;
#pragma unroll
    for (int i = 0; i < 4; ++i) {
      GLD16(baseA[i] + k0, As + ldso[i]);
      GLD16(baseB[i] + k0, Bs + ldso[i]);
    }
    __syncthreads();
#pragma unroll
    for (int kk = 0; kk < 2; ++kk) {
      int cb = ((kk * 4 + fg) ^ fsw) * 8;
      bf16x8 am[4], bn[4];
#pragma unroll
      for (int m = 0; m < 4; ++m)
        am[m] = *(const bf16x8*)(As + (wr * 64 + m * 16 + fr) * 64 + cb);
#pragma unroll
      for (int n = 0; n < 4; ++n)
        bn[n] = *(const bf16x8*)(Bs + (wc * 64 + n * 16 + fr) * 64 + cb);
#pragma unroll
      for (int m = 0; m < 4; ++m)
#pragma unroll
        for (int n = 0; n < 4; ++n)
          MFMA16x16x32(acc[m][n], am[m], bn[n]);
    }
    __syncthreads();
  }
#pragma unroll
  for (int m = 0; m < 4; ++m)
#pragma unroll
    for (int q = 0; q < 4; ++q) {
      int row = wr * 64 + m * 16 + fg * 4 + q;
      if (row < rcnt) {
        size_t ybase = (size_t)(hb + m0 + row) * H_DIM + n0 + wc * 64;
#pragma unroll
        for (int n = 0; n < 4; ++n)
          y[ybase + n * 16 + fr] = f2bf(acc[m][n][q]);
      }
    }
}

// ---------------- gather-combine: out[t] = w1*y[c1] + w2*y[c2] ----------------
__global__ __launch_bounds__(256) void combine_kernel(
    const unsigned short* __restrict__ y, const int* __restrict__ offs,
    const int* __restrict__ sA, const int* __restrict__ sB,
    const float* __restrict__ wA, const float* __restrict__ wB,
    float* __restrict__ out) {
  int t = blockIdx.x;
  int s1 = sA[t], s2 = sB[t];
  float w1 = wA[t], w2 = wB[t];
  int c1 = offs[s1 >> 13] + (s1 & (CAP - 1));
  int c2 = offs[s2 >> 13] + (s2 & (CAP - 1));
  int h = threadIdx.x * 4;
  ushort4 a = *(const ushort4*)(y + (size_t)c1 * H_DIM + h);
  ushort4 b = *(const ushort4*)(y + (size_t)c2 * H_DIM + h);
  float4 o;
  o.x = w1 * bf2f(a.x) + w2 * bf2f(b.x);
  o.y = w1 * bf2f(a.y) + w2 * bf2f(b.y);
  o.z = w1 * bf2f(a.z) + w2 * bf2f(b.z);
  o.w = w1 * bf2f(a.w) + w2 * bf2f(b.w);
  *(float4*)(out + (size_t)t * H_DIM + h) = o;
}

extern "C" void kernel_launch(void* const* d_in, const int* in_sizes, int n_in,
                              void* d_out, int out_size, void* d_ws, size_t ws_size,
                              hipStream_t stream) {
  const float* x   = (const float*)d_in[0];
  const float* wr  = (const float*)d_in[1];
  const float* wg  = (const float*)d_in[2];
  const float* wu  = (const float*)d_in[3];
  const float* wd  = (const float*)d_in[4];
  float* out = (float*)d_out;

  char* ws = (char*)d_ws;
  int*   cnt  = (int*)ws;                                   // 32 B
  int*   offs = (int*)(ws + 64);
  int*   tokL = (int*)(ws + 1024);                          // 256 KB
  int*   sA   = (int*)(ws + 1024 + 262144);                 // 32 KB
  int*   sB   = (int*)(ws + 1024 + 262144 + 32768);
  float* wA   = (float*)(ws + 1024 + 262144 + 65536);
  float* wB   = (float*)(ws + 1024 + 262144 + 98304);
  unsigned short* xb  = (unsigned short*)(ws + (1u << 20));
  unsigned short* wgT = (unsigned short*)(ws + (1u << 20) + (size_t)T_TOK * H_DIM * 2);
  unsigned short* wuT = wgT + (size_t)NEXP * I_DIM * H_DIM;
  unsigned short* wdT = wuT + (size_t)NEXP * I_DIM * H_DIM;
  unsigned short* hbuf = wdT + (size_t)NEXP * H_DIM * I_DIM;
  unsigned short* y    = hbuf + (size_t)2 * T_TOK * I_DIM;

  hipMemsetAsync(ws, 0, 64, stream);                        // counts

  router_kernel<<<T_TOK / 4, 256, 0, stream>>>(x, wr, cnt, tokL, sA, sB, wA, wB, xb);
  scan_kernel<<<1, 64, 0, stream>>>(cnt, offs);

  transposeGU_kernel<<<dim3(I_DIM / 64, H_DIM / 64, 16), 256, 0, stream>>>(wg, wu, wgT, wuT);
  transpose_kernel<<<dim3(H_DIM / 64, I_DIM / 64, NEXP), 256, 0, stream>>>(wd, wdT, I_DIM, H_DIM);

  gateup_kernel<<<dim3(I_DIM / 128, CAP / 128, NEXP), 256, 0, stream>>>(
      xb, wgT, wuT, cnt, offs, tokL, hbuf);
  down_kernel<<<dim3(H_DIM / 128, CAP / 128, NEXP), 256, 0, stream>>>(
      hbuf, wdT, cnt, offs, y);
  combine_kernel<<<T_TOK, 256, 0, stream>>>(y, offs, sA, sB, wA, wB, out);
}